// Round 2
// baseline (1970.591 us; speedup 1.0000x reference)
//
#include <hip/hip_runtime.h>
#include <hip/hip_bf16.h>

typedef __hip_bfloat16 bf16;

#define H_ 128
#define P_ 6
#define K_ 4

__device__ __forceinline__ float ldf(const float* p, size_t i) { return p[i]; }
__device__ __forceinline__ float ldf(const bf16* p, size_t i) { return __bfloat162float(p[i]); }

// ---------------- input embedding: t1 = relu(x * W1 + b1) ----------------
__global__ __launch_bounds__(128) void k_in_t1(const float* __restrict__ x,
    const float* __restrict__ W1, const float* __restrict__ b1, float* __restrict__ t1)
{
    int r = blockIdx.x, hd = threadIdx.x;
    t1[(size_t)r * H_ + hd] = fmaxf(fmaf(x[r], W1[hd], b1[hd]), 0.f);
}

// ---------------- generic fused block: out = [res +] relu(ln(relu(in@W1+b1)@W2+b2)*g+bn)
template<bool DO_MM1, bool HAS_RES>
__global__ __launch_bounds__(128) void k_block(
    const float* __restrict__ in, const float* __restrict__ res, float* __restrict__ out,
    const float* __restrict__ W1, const float* __restrict__ b1,
    const float* __restrict__ W2, const float* __restrict__ b2,
    const float* __restrict__ gam, const float* __restrict__ bet)
{
    __shared__ float sA[16][136];
    __shared__ float sB[16][136];
    __shared__ float sStat[32];
    const int hd = threadIdx.x;
    const size_t row0 = (size_t)blockIdx.x * 16;
    #pragma unroll
    for (int r = 0; r < 16; ++r) sA[r][hd] = in[(row0 + r) * H_ + hd];
    __syncthreads();
    float acc[16];
    if (DO_MM1) {
        #pragma unroll
        for (int r = 0; r < 16; ++r) acc[r] = b1[hd];
        for (int k = 0; k < H_; k += 4) {
            float w0 = W1[(k+0)*H_+hd], w1 = W1[(k+1)*H_+hd], w2 = W1[(k+2)*H_+hd], w3 = W1[(k+3)*H_+hd];
            #pragma unroll
            for (int r = 0; r < 16; ++r) {
                float4 a = *(const float4*)&sA[r][k];
                acc[r] = fmaf(a.x, w0, acc[r]); acc[r] = fmaf(a.y, w1, acc[r]);
                acc[r] = fmaf(a.z, w2, acc[r]); acc[r] = fmaf(a.w, w3, acc[r]);
            }
        }
        #pragma unroll
        for (int r = 0; r < 16; ++r) sB[r][hd] = fmaxf(acc[r], 0.f);
    } else {
        #pragma unroll
        for (int r = 0; r < 16; ++r) sB[r][hd] = sA[r][hd];
    }
    __syncthreads();
    #pragma unroll
    for (int r = 0; r < 16; ++r) acc[r] = b2[hd];
    for (int k = 0; k < H_; k += 4) {
        float w0 = W2[(k+0)*H_+hd], w1 = W2[(k+1)*H_+hd], w2 = W2[(k+2)*H_+hd], w3 = W2[(k+3)*H_+hd];
        #pragma unroll
        for (int r = 0; r < 16; ++r) {
            float4 a = *(const float4*)&sB[r][k];
            acc[r] = fmaf(a.x, w0, acc[r]); acc[r] = fmaf(a.y, w1, acc[r]);
            acc[r] = fmaf(a.z, w2, acc[r]); acc[r] = fmaf(a.w, w3, acc[r]);
        }
    }
    __syncthreads();
    #pragma unroll
    for (int r = 0; r < 16; ++r) sA[r][hd] = acc[r];
    __syncthreads();
    if (hd < 16) {
        float s = 0.f, ss = 0.f;
        for (int k = 0; k < H_; ++k) { float v = sA[hd][k]; s += v; ss += v * v; }
        float mean = s * (1.f / H_);
        float var = ss * (1.f / H_) - mean * mean;
        sStat[hd] = mean; sStat[16 + hd] = rsqrtf(var + 1e-5f);
    }
    __syncthreads();
    float gv = gam[hd], bv = bet[hd];
    #pragma unroll
    for (int r = 0; r < 16; ++r) {
        float v = fmaxf((acc[r] - sStat[r]) * sStat[16 + r] * gv + bv, 0.f);
        if (HAS_RES) v += res[(row0 + r) * H_ + hd];
        out[(row0 + r) * H_ + hd] = v;
    }
}

// ---------------- gemm + bias + relu (+ optional gathered residual from h) ----------------
template<bool GATHER, typename T>
__global__ __launch_bounds__(128) void k_gemm_relu(
    const T* __restrict__ in, const float* __restrict__ res, float* __restrict__ out,
    const float* __restrict__ W, const float* __restrict__ b)
{
    __shared__ float sA[16][136];
    const int hd = threadIdx.x;
    const size_t row0 = (size_t)blockIdx.x * 16;
    #pragma unroll
    for (int r = 0; r < 16; ++r) sA[r][hd] = ldf(in, (row0 + r) * H_ + hd);
    __syncthreads();
    float acc[16];
    #pragma unroll
    for (int r = 0; r < 16; ++r) acc[r] = b[hd];
    for (int k = 0; k < H_; k += 4) {
        float w0 = W[(k+0)*H_+hd], w1 = W[(k+1)*H_+hd], w2 = W[(k+2)*H_+hd], w3 = W[(k+3)*H_+hd];
        #pragma unroll
        for (int r = 0; r < 16; ++r) {
            float4 a = *(const float4*)&sA[r][k];
            acc[r] = fmaf(a.x, w0, acc[r]); acc[r] = fmaf(a.y, w1, acc[r]);
            acc[r] = fmaf(a.z, w2, acc[r]); acc[r] = fmaf(a.w, w3, acc[r]);
        }
    }
    #pragma unroll
    for (int r = 0; r < 16; ++r) {
        size_t rr = row0 + r;
        float v = fmaxf(acc[r], 0.f);
        if (GATHER) {
            int i = (int)(rr & 127);
            int g = (int)(rr >> 11);          // rr/(128*16)
            v += res[((size_t)(g * 128 + i)) * H_ + hd];
        }
        out[rr * H_ + hd] = v;
    }
}

// ---------------- sparse adjacency matvec ----------------
__global__ __launch_bounds__(128) void k_spmv(const float* __restrict__ adj,
    const float* __restrict__ xin, float* __restrict__ mout, int subShift)
{
    __shared__ float sAdj[128];
    const int hd = threadIdx.x;
    const int bi = blockIdx.x;
    const int bb = bi >> 7, i = bi & 127;
    const int g = bb >> subShift;
    sAdj[hd] = adj[((size_t)(g * 128 + i)) * 128 + hd];
    __syncthreads();
    float acc = 0.f;
    const float* xb = xin + (size_t)bb * 128 * H_ + hd;
    for (int j = 0; j < 128; ++j) {
        float a = sAdj[j];
        if (a != 0.f) acc = fmaf(a, xb[(size_t)j * H_], acc);
    }
    mout[(size_t)bi * H_ + hd] = acc;
}

// ---------------- ID layer 1, fully fused with z-init recompute ----------------
// z1[j,p,:] = 1 except labeled nodes -> idemb[allperm[q,p]]
// m1[i,p,:] = rowsum_i + sum_q a_{i,node_q} * (E[perm[q,p]] - 1)
// zout = z1 + block(m1)     (zout written bf16)
__global__ __launch_bounds__(128) void k_id_layer1(
    const float* __restrict__ adj, bf16* __restrict__ zout,
    const int* __restrict__ subgs, const int* __restrict__ allperm,
    const float* __restrict__ idemb,
    const float* __restrict__ W1, const float* __restrict__ b1,
    const float* __restrict__ W2, const float* __restrict__ b2,
    const float* __restrict__ gam, const float* __restrict__ bet)
{
    __shared__ float sAdj[128];
    __shared__ float sA[P_][136];
    __shared__ float sB[P_][136];
    __shared__ float sStat[2 * P_];
    __shared__ int sSub[K_];
    __shared__ int sPerm[K_ * P_];
    const int hd = threadIdx.x;
    const int bi = blockIdx.x;          // b_s*128 + i
    const int b_s = bi >> 7;
    const int i = bi & 127;
    const int g = b_s >> 4;
    sAdj[hd] = adj[((size_t)(g * 128 + i)) * 128 + hd];
    if (hd < K_) sSub[hd] = subgs[b_s * K_ + hd];
    if (hd < K_ * P_) sPerm[hd] = allperm[hd];
    __syncthreads();
    // per-thread idemb columns (values used are 0..K-1)
    float e[K_];
    #pragma unroll
    for (int v = 0; v < K_; ++v) e[v] = idemb[v * H_ + hd];
    // row sum + labeled-column coefficients
    float rowsum = 0.f;
    for (int j = 0; j < 128; ++j) rowsum += sAdj[j];
    float aq[K_];
    #pragma unroll
    for (int q = 0; q < K_; ++q) aq[q] = sAdj[sSub[q]];
    float acc[P_];
    #pragma unroll
    for (int p = 0; p < P_; ++p) {
        float m = rowsum;
        #pragma unroll
        for (int q = 0; q < K_; ++q) m = fmaf(aq[q], e[sPerm[q * P_ + p]] - 1.f, m);
        sA[p][hd] = m;
    }
    __syncthreads();
    #pragma unroll
    for (int p = 0; p < P_; ++p) acc[p] = b1[hd];
    for (int k = 0; k < H_; k += 4) {
        float w0 = W1[(k+0)*H_+hd], w1 = W1[(k+1)*H_+hd], w2 = W1[(k+2)*H_+hd], w3 = W1[(k+3)*H_+hd];
        #pragma unroll
        for (int p = 0; p < P_; ++p) {
            float4 a = *(const float4*)&sA[p][k];
            acc[p] = fmaf(a.x, w0, acc[p]); acc[p] = fmaf(a.y, w1, acc[p]);
            acc[p] = fmaf(a.z, w2, acc[p]); acc[p] = fmaf(a.w, w3, acc[p]);
        }
    }
    #pragma unroll
    for (int p = 0; p < P_; ++p) sB[p][hd] = fmaxf(acc[p], 0.f);
    __syncthreads();
    #pragma unroll
    for (int p = 0; p < P_; ++p) acc[p] = b2[hd];
    for (int k = 0; k < H_; k += 4) {
        float w0 = W2[(k+0)*H_+hd], w1 = W2[(k+1)*H_+hd], w2 = W2[(k+2)*H_+hd], w3 = W2[(k+3)*H_+hd];
        #pragma unroll
        for (int p = 0; p < P_; ++p) {
            float4 a = *(const float4*)&sB[p][k];
            acc[p] = fmaf(a.x, w0, acc[p]); acc[p] = fmaf(a.y, w1, acc[p]);
            acc[p] = fmaf(a.z, w2, acc[p]); acc[p] = fmaf(a.w, w3, acc[p]);
        }
    }
    __syncthreads();
    #pragma unroll
    for (int p = 0; p < P_; ++p) sA[p][hd] = acc[p];
    __syncthreads();
    if (hd < P_) {
        float s = 0.f, ss = 0.f;
        for (int k = 0; k < H_; ++k) { float v = sA[hd][k]; s += v; ss += v * v; }
        float mean = s * (1.f / H_);
        float var = ss * (1.f / H_) - mean * mean;
        sStat[hd] = mean; sStat[P_ + hd] = rsqrtf(var + 1e-5f);
    }
    __syncthreads();
    // self z1 row (for residual)
    int pos = -1;
    #pragma unroll
    for (int q = 0; q < K_; ++q) if (sSub[q] == i) pos = q;
    float gv = gam[hd], bv = bet[hd];
    const size_t ob = (size_t)bi * P_ * H_ + hd;
    #pragma unroll
    for (int p = 0; p < P_; ++p) {
        float self = (pos < 0) ? 1.f : e[sPerm[pos * P_ + p]];
        float v = fmaxf((acc[p] - sStat[p]) * sStat[P_ + p] * gv + bv, 0.f) + self;
        zout[ob + p * H_] = __float2bfloat16(v);
    }
}

// ---------------- ID layer 2 fused with masked mean over permutation channels ----------------
// zm[i,:] = mask * mean_p( zin[i,p,:] + block(sadj @ zin)[i,p,:] )   (bf16 out)
__global__ __launch_bounds__(128) void k_id_layer2_mean(
    const float* __restrict__ adj, const bf16* __restrict__ zin, bf16* __restrict__ zm,
    const int* __restrict__ num_node,
    const float* __restrict__ W1, const float* __restrict__ b1,
    const float* __restrict__ W2, const float* __restrict__ b2,
    const float* __restrict__ gam, const float* __restrict__ bet)
{
    __shared__ float sAdj[128];
    __shared__ float sA[P_][136];
    __shared__ float sB[P_][136];
    __shared__ float sStat[2 * P_];
    const int hd = threadIdx.x;
    const int bi = blockIdx.x;          // b_s*128 + i
    const int b_s = bi >> 7;
    const int i = bi & 127;
    const int g = b_s >> 4;
    sAdj[hd] = adj[((size_t)(g * 128 + i)) * 128 + hd];
    __syncthreads();
    float acc[P_] = {0.f, 0.f, 0.f, 0.f, 0.f, 0.f};
    const bf16* zb = zin + (size_t)b_s * 128 * P_ * H_ + hd;
    for (int j = 0; j < 128; ++j) {
        float a = sAdj[j];
        if (a != 0.f) {
            const bf16* zr = zb + (size_t)j * P_ * H_;
            #pragma unroll
            for (int p = 0; p < P_; ++p) acc[p] = fmaf(a, __bfloat162float(zr[p * H_]), acc[p]);
        }
    }
    #pragma unroll
    for (int p = 0; p < P_; ++p) sA[p][hd] = acc[p];
    __syncthreads();
    #pragma unroll
    for (int p = 0; p < P_; ++p) acc[p] = b1[hd];
    for (int k = 0; k < H_; k += 4) {
        float w0 = W1[(k+0)*H_+hd], w1 = W1[(k+1)*H_+hd], w2 = W1[(k+2)*H_+hd], w3 = W1[(k+3)*H_+hd];
        #pragma unroll
        for (int p = 0; p < P_; ++p) {
            float4 a = *(const float4*)&sA[p][k];
            acc[p] = fmaf(a.x, w0, acc[p]); acc[p] = fmaf(a.y, w1, acc[p]);
            acc[p] = fmaf(a.z, w2, acc[p]); acc[p] = fmaf(a.w, w3, acc[p]);
        }
    }
    #pragma unroll
    for (int p = 0; p < P_; ++p) sB[p][hd] = fmaxf(acc[p], 0.f);
    __syncthreads();
    #pragma unroll
    for (int p = 0; p < P_; ++p) acc[p] = b2[hd];
    for (int k = 0; k < H_; k += 4) {
        float w0 = W2[(k+0)*H_+hd], w1 = W2[(k+1)*H_+hd], w2 = W2[(k+2)*H_+hd], w3 = W2[(k+3)*H_+hd];
        #pragma unroll
        for (int p = 0; p < P_; ++p) {
            float4 a = *(const float4*)&sB[p][k];
            acc[p] = fmaf(a.x, w0, acc[p]); acc[p] = fmaf(a.y, w1, acc[p]);
            acc[p] = fmaf(a.z, w2, acc[p]); acc[p] = fmaf(a.w, w3, acc[p]);
        }
    }
    __syncthreads();
    #pragma unroll
    for (int p = 0; p < P_; ++p) sA[p][hd] = acc[p];
    __syncthreads();
    if (hd < P_) {
        float s = 0.f, ss = 0.f;
        for (int k = 0; k < H_; ++k) { float v = sA[hd][k]; s += v; ss += v * v; }
        float mean = s * (1.f / H_);
        float var = ss * (1.f / H_) - mean * mean;
        sStat[hd] = mean; sStat[P_ + hd] = rsqrtf(var + 1e-5f);
    }
    __syncthreads();
    float gv = gam[hd], bv = bet[hd];
    const size_t ob = (size_t)bi * P_ * H_ + hd;
    float s = 0.f;
    #pragma unroll
    for (int p = 0; p < P_; ++p) {
        float v = fmaxf((acc[p] - sStat[p]) * sStat[P_ + p] * gv + bv, 0.f);
        s += v + __bfloat162float(zin[ob + p * H_]);
    }
    s *= (1.f / P_);
    if (i >= num_node[g]) s = 0.f;
    zm[(size_t)bi * H_ + hd] = __float2bfloat16(s);
}

// ---------------- hs.sum(axis=1) ----------------
__global__ __launch_bounds__(128) void k_hssum(const float* __restrict__ hs, float* __restrict__ hsum)
{
    const int b_s = blockIdx.x, hd = threadIdx.x;
    float v = 0.f;
    const float* r = hs + (size_t)b_s * 128 * H_ + hd;
    for (int i = 0; i < 128; ++i) v += r[(size_t)i * H_];
    hsum[(size_t)b_s * H_ + hd] = v;
}

// ---------------- segment max over 16 subgraphs per graph ----------------
__global__ __launch_bounds__(128) void k_maxpool(const float* __restrict__ hs2, float* __restrict__ pooled)
{
    const int g = blockIdx.x, hd = threadIdx.x;
    float m = -INFINITY;
    for (int s = 0; s < 16; ++s) m = fmaxf(m, hs2[((size_t)(g * 16 + s)) * H_ + hd]);
    pooled[(size_t)g * H_ + hd] = m;
}

// ---------------- final projection ----------------
__global__ __launch_bounds__(128) void k_out(const float* __restrict__ pooled2,
    const float* __restrict__ out_W, const float* __restrict__ out_b, float* __restrict__ out)
{
    __shared__ float red[128];
    const int g = blockIdx.x, hd = threadIdx.x;
    red[hd] = pooled2[(size_t)g * H_ + hd] * out_W[hd];
    __syncthreads();
    for (int s = 64; s > 0; s >>= 1) {
        if (hd < s) red[hd] += red[hd + s];
        __syncthreads();
    }
    if (hd == 0) out[g] = red[0] + out_b[0];
}

extern "C" void kernel_launch(void* const* d_in, const int* in_sizes, int n_in,
                              void* d_out, int out_size, void* d_ws, size_t ws_size,
                              hipStream_t stream)
{
    (void)in_sizes; (void)n_in; (void)out_size; (void)ws_size;
    const float* x     = (const float*)d_in[0];
    const float* adj   = (const float*)d_in[1];
    const float* idemb = (const float*)d_in[2];
    const float* in_W1 = (const float*)d_in[3];
    const float* in_b1 = (const float*)d_in[4];
    const float* in_W2 = (const float*)d_in[5];
    const float* in_b2 = (const float*)d_in[6];
    const float* in_g  = (const float*)d_in[7];
    const float* in_bn = (const float*)d_in[8];
    const float* gW1   = (const float*)d_in[9];
    const float* gb1   = (const float*)d_in[10];
    const float* gW2   = (const float*)d_in[11];
    const float* gb2   = (const float*)d_in[12];
    const float* gg    = (const float*)d_in[13];
    const float* gbn   = (const float*)d_in[14];
    const float* iW1   = (const float*)d_in[15];
    const float* ib1   = (const float*)d_in[16];
    const float* iW2   = (const float*)d_in[17];
    const float* ib2   = (const float*)d_in[18];
    const float* ig    = (const float*)d_in[19];
    const float* ibn   = (const float*)d_in[20];
    const float* glW1  = (const float*)d_in[21];
    const float* glb1  = (const float*)d_in[22];
    const float* glW2  = (const float*)d_in[23];
    const float* glb2  = (const float*)d_in[24];
    const float* glg   = (const float*)d_in[25];
    const float* glbn  = (const float*)d_in[26];
    const float* s1_W  = (const float*)d_in[27];
    const float* s1_b  = (const float*)d_in[28];
    const float* s2_W  = (const float*)d_in[29];
    const float* s2_b  = (const float*)d_in[30];
    const float* rW1   = (const float*)d_in[31];
    const float* rb1   = (const float*)d_in[32];
    const float* rW2   = (const float*)d_in[33];
    const float* rb2   = (const float*)d_in[34];
    const float* rg    = (const float*)d_in[35];
    const float* rbn   = (const float*)d_in[36];
    const float* out_W = (const float*)d_in[37];
    const float* out_b = (const float*)d_in[38];
    const int* subgs   = (const int*)d_in[39];
    const int* num_node= (const int*)d_in[41];
    const int* allperm = (const int*)d_in[42];

    // ---- workspace layout (peak ~117 MB) ----
    const size_t ZBYTES = (size_t)512 * 128 * P_ * H_ * 2;     // 100,663,296 (region A)
    char* w = (char*)d_ws;
    bf16*  z      = (bf16*)(w);                                 // region A: z (id layers)
    float* hsb    = (float*)(w);                                // region A reuse: hs (512,128,128) f32
    float* ms     = (float*)(w + 33554432ull);                  // region A reuse: gl messages
    bf16*  zm     = (bf16*)(w + ZBYTES);                        // (512,128,128) bf16 = 16.8 MB
    char*  wc     = w + ZBYTES + 16777216ull;
    float* hb     = (float*)(wc);                               // h (32,128,128) f32  2 MB
    float* sb2    = (float*)(wc + 2097152ull);                  // t1 / g-layer msgs    2 MB
    float* hsum   = (float*)(wc + 4194304ull);                  // (512,128)
    float* hs2    = (float*)(wc + 4456448ull);                  // (512,128)
    float* pooled = (float*)(wc + 4718592ull);                  // (32,128)
    float* pooled2= (float*)(wc + 4734976ull);                  // (32,128)
    float* outp   = (float*)d_out;

    // input embedding block: h = block(x)
    k_in_t1<<<4096, 128, 0, stream>>>(x, in_W1, in_b1, sb2);
    k_block<false, false><<<256, 128, 0, stream>>>(sb2, nullptr, hb,
        nullptr, nullptr, in_W2, in_b2, in_g, in_bn);

    // graph message passing (3 layers) on h
    for (int l = 0; l < 3; ++l) {
        k_spmv<<<4096, 128, 0, stream>>>(adj, hb, sb2, 0);
        k_block<true, true><<<256, 128, 0, stream>>>(sb2, hb, hb,
            gW1 + l * 16384, gb1 + l * 128, gW2 + l * 16384, gb2 + l * 128,
            gg + l * 128, gbn + l * 128);
    }

    // ID layer 1 (z-init recomputed inline) -> z ; ID layer 2 fused with masked p-mean -> zm
    k_id_layer1<<<65536, 128, 0, stream>>>(adj, z, subgs, allperm, idemb,
        iW1, ib1, iW2, ib2, ig, ibn);
    k_id_layer2_mean<<<65536, 128, 0, stream>>>(adj, z, zm, num_node,
        iW1 + 16384, ib1 + 128, iW2 + 16384, ib2 + 128, ig + 128, ibn + 128);

    // setmlp1 with gathered residual h[subgbatch] -> hsb (region A; z now dead)
    k_gemm_relu<true, bf16><<<4096, 128, 0, stream>>>(zm, hb, hsb, s1_W, s1_b);

    // global message passing on subgraph copies (2 layers)
    for (int l = 0; l < 2; ++l) {
        k_spmv<<<65536, 128, 0, stream>>>(adj, hsb, ms, 4);
        k_block<true, true><<<4096, 128, 0, stream>>>(ms, hsb, hsb,
            glW1 + l * 16384, glb1 + l * 128, glW2 + l * 16384, glb2 + l * 128,
            glg + l * 128, glbn + l * 128);
    }

    // node sum -> setmlp2 -> segment max -> setmlp3 block -> output proj
    k_hssum<<<512, 128, 0, stream>>>(hsb, hsum);
    k_gemm_relu<false, float><<<32, 128, 0, stream>>>(hsum, nullptr, hs2, s2_W, s2_b);
    k_maxpool<<<32, 128, 0, stream>>>(hs2, pooled);
    k_block<true, true><<<2, 128, 0, stream>>>(pooled, pooled, pooled2,
        rW1, rb1, rW2, rb2, rg, rbn);
    k_out<<<32, 128, 0, stream>>>(pooled2, out_W, out_b, outp);
}

// Round 3
// 1058.873 us; speedup vs baseline: 1.8610x; 1.8610x over previous
//
#include <hip/hip_runtime.h>
#include <hip/hip_bf16.h>
#include <string.h>

typedef __hip_bfloat16 bf16;
typedef short v8s __attribute__((ext_vector_type(8)));
typedef float v4f __attribute__((ext_vector_type(4)));

#define H_ 128
#define P_ 6
#define K_ 4
#define NBR_CAP 48

__device__ __forceinline__ float ldf(const float* p, size_t i) { return p[i]; }
__device__ __forceinline__ float ldf(const bf16* p, size_t i) { return __bfloat162float(p[i]); }

__device__ __forceinline__ float s2f(short s) {
    unsigned int u = ((unsigned int)(unsigned short)s) << 16;
    float f; __builtin_memcpy(&f, &u, 4); return f;
}
__device__ __forceinline__ short f2s(float v) {
    bf16 h = __float2bfloat16(v);
    short s; __builtin_memcpy(&s, &h, 2); return s;
}
__device__ __forceinline__ v4f MFMA(v8s a, v8s b, v4f c) {
    return __builtin_amdgcn_mfma_f32_16x16x32_bf16(a, b, c, 0, 0, 0);
}

// ---------------- CSR build: neighbor u8 lists + degree + float rowsum ----------------
__global__ __launch_bounds__(128) void k_csr(const float* __restrict__ adj,
    unsigned char* __restrict__ nbr, int* __restrict__ deg, float* __restrict__ degf)
{
    const int gi = blockIdx.x * 128 + threadIdx.x;   // (g,i), 4096 rows
    const float* row = adj + (size_t)gi * 128;
    unsigned char* nb = nbr + (size_t)gi * NBR_CAP;
    int c = 0; float s = 0.f;
    for (int j = 0; j < 128; ++j) {
        float a = row[j];
        if (a != 0.f) { s += a; if (c < NBR_CAP) nb[c] = (unsigned char)j; ++c; }
    }
    deg[gi] = (c < NBR_CAP) ? c : NBR_CAP;
    degf[gi] = s;
}

// ---------------- transpose 8 (128x128) weights to bf16 WT[n][k] ----------------
__global__ __launch_bounds__(128) void k_wt8(
    const float* s0, const float* s1, const float* s2, const float* s3,
    const float* s4, const float* s5, const float* s6, const float* s7,
    bf16* __restrict__ dst)
{
    const int w = blockIdx.x >> 7, n = blockIdx.x & 127, k = threadIdx.x;
    const float* arr[8] = {s0, s1, s2, s3, s4, s5, s6, s7};
    dst[(size_t)w * 16384 + n * 128 + k] = __float2bfloat16(arr[w][k * 128 + n]);
}

// ---------------- input embedding: t1 = relu(x * W1 + b1) ----------------
__global__ __launch_bounds__(128) void k_in_t1(const float* __restrict__ x,
    const float* __restrict__ W1, const float* __restrict__ b1, float* __restrict__ t1)
{
    int r = blockIdx.x, hd = threadIdx.x;
    t1[(size_t)r * H_ + hd] = fmaxf(fmaf(x[r], W1[hd], b1[hd]), 0.f);
}

// ---------------- generic VALU fused block (used for small row counts) ----------------
template<bool DO_MM1, bool HAS_RES>
__global__ __launch_bounds__(128) void k_block(
    const float* __restrict__ in, const float* __restrict__ res, float* __restrict__ out,
    const float* __restrict__ W1, const float* __restrict__ b1,
    const float* __restrict__ W2, const float* __restrict__ b2,
    const float* __restrict__ gam, const float* __restrict__ bet)
{
    __shared__ float sA[16][136];
    __shared__ float sB[16][136];
    __shared__ float sStat[32];
    const int hd = threadIdx.x;
    const size_t row0 = (size_t)blockIdx.x * 16;
    #pragma unroll
    for (int r = 0; r < 16; ++r) sA[r][hd] = in[(row0 + r) * H_ + hd];
    __syncthreads();
    float acc[16];
    if (DO_MM1) {
        #pragma unroll
        for (int r = 0; r < 16; ++r) acc[r] = b1[hd];
        for (int k = 0; k < H_; k += 4) {
            float w0 = W1[(k+0)*H_+hd], w1 = W1[(k+1)*H_+hd], w2 = W1[(k+2)*H_+hd], w3 = W1[(k+3)*H_+hd];
            #pragma unroll
            for (int r = 0; r < 16; ++r) {
                float4 a = *(const float4*)&sA[r][k];
                acc[r] = fmaf(a.x, w0, acc[r]); acc[r] = fmaf(a.y, w1, acc[r]);
                acc[r] = fmaf(a.z, w2, acc[r]); acc[r] = fmaf(a.w, w3, acc[r]);
            }
        }
        #pragma unroll
        for (int r = 0; r < 16; ++r) sB[r][hd] = fmaxf(acc[r], 0.f);
    } else {
        #pragma unroll
        for (int r = 0; r < 16; ++r) sB[r][hd] = sA[r][hd];
    }
    __syncthreads();
    #pragma unroll
    for (int r = 0; r < 16; ++r) acc[r] = b2[hd];
    for (int k = 0; k < H_; k += 4) {
        float w0 = W2[(k+0)*H_+hd], w1 = W2[(k+1)*H_+hd], w2 = W2[(k+2)*H_+hd], w3 = W2[(k+3)*H_+hd];
        #pragma unroll
        for (int r = 0; r < 16; ++r) {
            float4 a = *(const float4*)&sB[r][k];
            acc[r] = fmaf(a.x, w0, acc[r]); acc[r] = fmaf(a.y, w1, acc[r]);
            acc[r] = fmaf(a.z, w2, acc[r]); acc[r] = fmaf(a.w, w3, acc[r]);
        }
    }
    __syncthreads();
    #pragma unroll
    for (int r = 0; r < 16; ++r) sA[r][hd] = acc[r];
    __syncthreads();
    if (hd < 16) {
        float s = 0.f, ss = 0.f;
        for (int k = 0; k < H_; ++k) { float v = sA[hd][k]; s += v; ss += v * v; }
        float mean = s * (1.f / H_);
        float var = ss * (1.f / H_) - mean * mean;
        sStat[hd] = mean; sStat[16 + hd] = rsqrtf(var + 1e-5f);
    }
    __syncthreads();
    float gv = gam[hd], bv = bet[hd];
    #pragma unroll
    for (int r = 0; r < 16; ++r) {
        float v = fmaxf((acc[r] - sStat[r]) * sStat[16 + r] * gv + bv, 0.f);
        if (HAS_RES) v += res[(row0 + r) * H_ + hd];
        out[(row0 + r) * H_ + hd] = v;
    }
}

// ---------------- gemm + bias + relu (+ optional gathered residual from h) ----------------
template<bool GATHER, typename T>
__global__ __launch_bounds__(128) void k_gemm_relu(
    const T* __restrict__ in, const float* __restrict__ res, float* __restrict__ out,
    const float* __restrict__ W, const float* __restrict__ b)
{
    __shared__ float sA[16][136];
    const int hd = threadIdx.x;
    const size_t row0 = (size_t)blockIdx.x * 16;
    #pragma unroll
    for (int r = 0; r < 16; ++r) sA[r][hd] = ldf(in, (row0 + r) * H_ + hd);
    __syncthreads();
    float acc[16];
    #pragma unroll
    for (int r = 0; r < 16; ++r) acc[r] = b[hd];
    for (int k = 0; k < H_; k += 4) {
        float w0 = W[(k+0)*H_+hd], w1 = W[(k+1)*H_+hd], w2 = W[(k+2)*H_+hd], w3 = W[(k+3)*H_+hd];
        #pragma unroll
        for (int r = 0; r < 16; ++r) {
            float4 a = *(const float4*)&sA[r][k];
            acc[r] = fmaf(a.x, w0, acc[r]); acc[r] = fmaf(a.y, w1, acc[r]);
            acc[r] = fmaf(a.z, w2, acc[r]); acc[r] = fmaf(a.w, w3, acc[r]);
        }
    }
    #pragma unroll
    for (int r = 0; r < 16; ++r) {
        size_t rr = row0 + r;
        float v = fmaxf(acc[r], 0.f);
        if (GATHER) {
            int i = (int)(rr & 127);
            int g = (int)(rr >> 11);          // rr/(128*16)
            v += res[((size_t)(g * 128 + i)) * H_ + hd];
        }
        out[rr * H_ + hd] = v;
    }
}

// ---------------- dense sparse-matvec for g-layers (small, keep VALU) ----------------
__global__ __launch_bounds__(128) void k_spmv(const float* __restrict__ adj,
    const float* __restrict__ xin, float* __restrict__ mout, int subShift)
{
    __shared__ float sAdj[128];
    const int hd = threadIdx.x;
    const int bi = blockIdx.x;
    const int bb = bi >> 7, i = bi & 127;
    const int g = bb >> subShift;
    sAdj[hd] = adj[((size_t)(g * 128 + i)) * 128 + hd];
    __syncthreads();
    float acc = 0.f;
    const float* xb = xin + (size_t)bb * 128 * H_ + hd;
    for (int j = 0; j < 128; ++j) {
        float a = sAdj[j];
        if (a != 0.f) acc = fmaf(a, xb[(size_t)j * H_], acc);
    }
    mout[(size_t)bi * H_ + hd] = acc;
}

// ---------------- m1 for ID layer 1 (z1 recomputed in closed form) ----------------
__global__ __launch_bounds__(128) void k_m1(
    const float* __restrict__ adj, const float* __restrict__ degf,
    const int* __restrict__ subgs, const int* __restrict__ allperm,
    const float* __restrict__ idemb, bf16* __restrict__ mout)
{
    const int hd = threadIdx.x;
    const int bi = blockIdx.x;           // b_s*128 + i
    const int b_s = bi >> 7, i = bi & 127, g = b_s >> 4;
    const int gi = g * 128 + i;
    const float dg = degf[gi];
    float aq[K_]; int sub[K_];
    #pragma unroll
    for (int q = 0; q < K_; ++q) {
        sub[q] = subgs[b_s * K_ + q];
        aq[q] = adj[(size_t)gi * 128 + sub[q]];
    }
    #pragma unroll
    for (int p = 0; p < P_; ++p) {
        float v = dg;
        #pragma unroll
        for (int q = 0; q < K_; ++q)
            if (aq[q] != 0.f) v += aq[q] * (idemb[allperm[q * P_ + p] * H_ + hd] - 1.f);
        mout[((size_t)bi * P_ + p) * H_ + hd] = __float2bfloat16(v);
    }
}

// ---------------- MFMA fused MLP block: out = res + relu(ln(relu(m@W1+b1)@W2+b2)*g+bn)
// RES==0: residual = +1.0, bf16 out (ID layer 1, in-place over m)
// RES==2: residual = resf (f32), f32 out (gl layers, in-place over resf)
template<int RES>
__global__ __launch_bounds__(256) void k_mlp_mfma(
    const bf16* __restrict__ m, const float* __restrict__ resf,
    bf16* __restrict__ outb, float* __restrict__ outf,
    const bf16* __restrict__ W1t, const float* __restrict__ b1,
    const bf16* __restrict__ W2t, const float* __restrict__ b2,
    const float* __restrict__ gam, const float* __restrict__ bet)
{
    __shared__ __align__(16) short tb[4][32][136];
    const int wave = threadIdx.x >> 6, lane = threadIdx.x & 63;
    const int quad = lane >> 4, l16 = lane & 15;
    const size_t row0 = (size_t)blockIdx.x * 128 + wave * 32;
    v4f acc[2][8];
    #pragma unroll
    for (int mt = 0; mt < 2; ++mt)
        #pragma unroll
        for (int nt = 0; nt < 8; ++nt) acc[mt][nt] = (v4f){0.f, 0.f, 0.f, 0.f};
    // MM1: t = relu(m @ W1 + b1)
    #pragma unroll
    for (int kk = 0; kk < 4; ++kk) {
        v8s a0 = *(const v8s*)(m + (row0 + l16) * 128 + kk * 32 + quad * 8);
        v8s a1 = *(const v8s*)(m + (row0 + 16 + l16) * 128 + kk * 32 + quad * 8);
        #pragma unroll
        for (int nt = 0; nt < 8; ++nt) {
            v8s b = *(const v8s*)(W1t + (nt * 16 + l16) * 128 + kk * 32 + quad * 8);
            acc[0][nt] = MFMA(a0, b, acc[0][nt]);
            acc[1][nt] = MFMA(a1, b, acc[1][nt]);
        }
    }
    #pragma unroll
    for (int nt = 0; nt < 8; ++nt) {
        float bb = b1[nt * 16 + l16];
        #pragma unroll
        for (int mt = 0; mt < 2; ++mt)
            #pragma unroll
            for (int r = 0; r < 4; ++r)
                tb[wave][mt * 16 + quad * 4 + r][nt * 16 + l16] = f2s(fmaxf(acc[mt][nt][r] + bb, 0.f));
    }
    // MM2: u = t @ W2 + b2
    #pragma unroll
    for (int mt = 0; mt < 2; ++mt)
        #pragma unroll
        for (int nt = 0; nt < 8; ++nt) acc[mt][nt] = (v4f){0.f, 0.f, 0.f, 0.f};
    #pragma unroll
    for (int kk = 0; kk < 4; ++kk) {
        v8s a0 = *(const v8s*)&tb[wave][l16][kk * 32 + quad * 8];
        v8s a1 = *(const v8s*)&tb[wave][16 + l16][kk * 32 + quad * 8];
        #pragma unroll
        for (int nt = 0; nt < 8; ++nt) {
            v8s b = *(const v8s*)(W2t + (nt * 16 + l16) * 128 + kk * 32 + quad * 8);
            acc[0][nt] = MFMA(a0, b, acc[0][nt]);
            acc[1][nt] = MFMA(a1, b, acc[1][nt]);
        }
    }
    // epilogue: bias, LN (per row), relu, residual, store
    float bb2[8], gv[8], bv[8];
    #pragma unroll
    for (int nt = 0; nt < 8; ++nt) {
        int n = nt * 16 + l16;
        bb2[nt] = b2[n]; gv[nt] = gam[n]; bv[nt] = bet[n];
    }
    float mean[2][4], rstd[2][4];
    #pragma unroll
    for (int mt = 0; mt < 2; ++mt)
        #pragma unroll
        for (int r = 0; r < 4; ++r) {
            float s = 0.f, q = 0.f;
            #pragma unroll
            for (int nt = 0; nt < 8; ++nt) {
                float u = acc[mt][nt][r] + bb2[nt];
                acc[mt][nt][r] = u;
                s += u; q += u * u;
            }
            #pragma unroll
            for (int d = 1; d < 16; d <<= 1) {
                s += __shfl_xor(s, d);
                q += __shfl_xor(q, d);
            }
            float mn = s * (1.f / 128.f);
            mean[mt][r] = mn;
            rstd[mt][r] = rsqrtf(q * (1.f / 128.f) - mn * mn + 1e-5f);
        }
    #pragma unroll
    for (int mt = 0; mt < 2; ++mt)
        #pragma unroll
        for (int nt = 0; nt < 8; ++nt)
            #pragma unroll
            for (int r = 0; r < 4; ++r) {
                size_t rg = row0 + mt * 16 + quad * 4 + r;
                int col = nt * 16 + l16;
                float v = fmaxf((acc[mt][nt][r] - mean[mt][r]) * rstd[mt][r] * gv[nt] + bv[nt], 0.f);
                if (RES == 0) outb[rg * 128 + col] = __float2bfloat16(v + 1.0f);
                else          outf[rg * 128 + col] = v + resf[rg * 128 + col];
            }
}

// ---------------- patch layer-1 residual at labeled nodes: z2 += e - 1 ----------------
__global__ __launch_bounds__(128) void k_addself(bf16* __restrict__ z2,
    const int* __restrict__ subgs, const int* __restrict__ allperm,
    const float* __restrict__ idemb)
{
    const int b_s = blockIdx.x >> 2, q = blockIdx.x & 3, hd = threadIdx.x;
    const int node = subgs[b_s * K_ + q];
    #pragma unroll
    for (int p = 0; p < P_; ++p) {
        float ev = idemb[allperm[q * P_ + p] * H_ + hd] - 1.f;
        size_t idx = (((size_t)(b_s * 128 + node)) * P_ + p) * H_ + hd;
        z2[idx] = __float2bfloat16(__bfloat162float(z2[idx]) + ev);
    }
}

// ---------------- ID layer 2, fully fused: gather-spmv -> MLP -> LN -> residual -> p-mean
// block = 32 nodes of one subgraph (192 rows); writes only zm (bf16 512x128x128)
__global__ __launch_bounds__(256) void k_id2_fused(
    const bf16* __restrict__ z2, bf16* __restrict__ zm,
    const unsigned char* __restrict__ nbr, const int* __restrict__ deg,
    const int* __restrict__ num_node,
    const bf16* __restrict__ W1t, const float* __restrict__ b1,
    const bf16* __restrict__ W2t, const float* __restrict__ b2,
    const float* __restrict__ gam, const float* __restrict__ bet)
{
    __shared__ __align__(16) short smem[4][48][136];
    const int t = threadIdx.x;
    const int b_s = blockIdx.x >> 2;
    const int node0 = (blockIdx.x & 3) * 32;
    const int g = b_s >> 4;
    // ---- stage 1: m rows (gather-sum of neighbors' z2) into LDS ----
    if (t < 192) {
        const int il = t / 6, p = t % 6;
        const int gi = g * 128 + node0 + il;
        const int cnt = deg[gi];
        const unsigned char* nb = nbr + (size_t)gi * NBR_CAP;
        const bf16* zb = z2 + ((size_t)b_s * 128) * (P_ * H_) + p * H_;
        #pragma unroll
        for (int hc = 0; hc < 4; ++hc) {
            float a[32];
            #pragma unroll
            for (int u = 0; u < 32; ++u) a[u] = 0.f;
            for (int c = 0; c < cnt; ++c) {
                const v8s* zr = (const v8s*)(zb + (size_t)nb[c] * (P_ * H_) + hc * 32);
                #pragma unroll
                for (int q2 = 0; q2 < 4; ++q2) {
                    v8s v = zr[q2];
                    #pragma unroll
                    for (int u = 0; u < 8; ++u) a[q2 * 8 + u] += s2f(v[u]);
                }
            }
            short* dst = &smem[t / 48][t % 48][hc * 32];
            #pragma unroll
            for (int u = 0; u < 32; ++u) dst[u] = f2s(a[u]);
        }
    }
    __syncthreads();
    // ---- stage 2: MFMA MLP on 48 rows per wave ----
    const int lane = t & 63, wave = t >> 6;
    const int quad = lane >> 4, l16 = lane & 15;
    v4f acc[3][8];
    #pragma unroll
    for (int mt = 0; mt < 3; ++mt)
        #pragma unroll
        for (int nt = 0; nt < 8; ++nt) acc[mt][nt] = (v4f){0.f, 0.f, 0.f, 0.f};
    #pragma unroll
    for (int kk = 0; kk < 4; ++kk) {
        v8s a0 = *(const v8s*)&smem[wave][l16][kk * 32 + quad * 8];
        v8s a1 = *(const v8s*)&smem[wave][16 + l16][kk * 32 + quad * 8];
        v8s a2 = *(const v8s*)&smem[wave][32 + l16][kk * 32 + quad * 8];
        #pragma unroll
        for (int nt = 0; nt < 8; ++nt) {
            v8s b = *(const v8s*)(W1t + (nt * 16 + l16) * 128 + kk * 32 + quad * 8);
            acc[0][nt] = MFMA(a0, b, acc[0][nt]);
            acc[1][nt] = MFMA(a1, b, acc[1][nt]);
            acc[2][nt] = MFMA(a2, b, acc[2][nt]);
        }
    }
    #pragma unroll
    for (int nt = 0; nt < 8; ++nt) {
        float bb = b1[nt * 16 + l16];
        #pragma unroll
        for (int mt = 0; mt < 3; ++mt)
            #pragma unroll
            for (int r = 0; r < 4; ++r)
                smem[wave][mt * 16 + quad * 4 + r][nt * 16 + l16] = f2s(fmaxf(acc[mt][nt][r] + bb, 0.f));
    }
    #pragma unroll
    for (int mt = 0; mt < 3; ++mt)
        #pragma unroll
        for (int nt = 0; nt < 8; ++nt) acc[mt][nt] = (v4f){0.f, 0.f, 0.f, 0.f};
    #pragma unroll
    for (int kk = 0; kk < 4; ++kk) {
        v8s a0 = *(const v8s*)&smem[wave][l16][kk * 32 + quad * 8];
        v8s a1 = *(const v8s*)&smem[wave][16 + l16][kk * 32 + quad * 8];
        v8s a2 = *(const v8s*)&smem[wave][32 + l16][kk * 32 + quad * 8];
        #pragma unroll
        for (int nt = 0; nt < 8; ++nt) {
            v8s b = *(const v8s*)(W2t + (nt * 16 + l16) * 128 + kk * 32 + quad * 8);
            acc[0][nt] = MFMA(a0, b, acc[0][nt]);
            acc[1][nt] = MFMA(a1, b, acc[1][nt]);
            acc[2][nt] = MFMA(a2, b, acc[2][nt]);
        }
    }
    // ---- stage 3: bias, LN, relu, + z2 residual -> back to LDS (bf16) ----
    float bb2[8], gv[8], bv[8];
    #pragma unroll
    for (int nt = 0; nt < 8; ++nt) {
        int n = nt * 16 + l16;
        bb2[nt] = b2[n]; gv[nt] = gam[n]; bv[nt] = bet[n];
    }
    const size_t rowbase = ((size_t)(b_s * 128 + node0)) * P_;
    #pragma unroll
    for (int mt = 0; mt < 3; ++mt)
        #pragma unroll
        for (int r = 0; r < 4; ++r) {
            float s = 0.f, q = 0.f;
            #pragma unroll
            for (int nt = 0; nt < 8; ++nt) {
                float u = acc[mt][nt][r] + bb2[nt];
                acc[mt][nt][r] = u;
                s += u; q += u * u;
            }
            #pragma unroll
            for (int d = 1; d < 16; d <<= 1) {
                s += __shfl_xor(s, d);
                q += __shfl_xor(q, d);
            }
            float mn = s * (1.f / 128.f);
            float rs = rsqrtf(q * (1.f / 128.f) - mn * mn + 1e-5f);
            #pragma unroll
            for (int nt = 0; nt < 8; ++nt) {
                int lr = wave * 48 + mt * 16 + quad * 4 + r;
                int col = nt * 16 + l16;
                float v = fmaxf((acc[mt][nt][r] - mn) * rs * gv[nt] + bv[nt], 0.f);
                v += __bfloat162float(z2[(rowbase + lr) * 128 + col]);
                smem[wave][mt * 16 + quad * 4 + r][col] = f2s(v);
            }
        }
    // ---- stage 4: p-mean per node (wave-private rows), masked, write zm ----
    const int n_l = lane >> 3, c0 = (lane & 7) * 16;
    const int i_g = node0 + wave * 8 + n_l;
    float sum[16];
    #pragma unroll
    for (int u = 0; u < 16; ++u) sum[u] = 0.f;
    #pragma unroll
    for (int p = 0; p < P_; ++p) {
        const v8s* pr = (const v8s*)&smem[wave][n_l * 6 + p][c0];
        v8s v0 = pr[0], v1 = pr[1];
        #pragma unroll
        for (int u = 0; u < 8; ++u) { sum[u] += s2f(v0[u]); sum[8 + u] += s2f(v1[u]); }
    }
    const bool nul = (i_g >= num_node[g]);
    bf16* zd = zm + ((size_t)(b_s * 128 + i_g)) * 128 + c0;
    #pragma unroll
    for (int u = 0; u < 16; ++u) zd[u] = __float2bfloat16(nul ? 0.f : sum[u] * (1.f / 6.f));
}

// ---------------- gather-spmv for gl layers: m = sum_{j in N(i)} hs[j] (bf16 out) ----------------
__global__ __launch_bounds__(128) void k_spm_gl(const float* __restrict__ hs,
    bf16* __restrict__ mout, const unsigned char* __restrict__ nbr, const int* __restrict__ deg)
{
    const int hd = threadIdx.x, bi = blockIdx.x;
    const int b_s = bi >> 7, i = bi & 127;
    const int gi = ((b_s >> 4) << 7) + i;
    const int cnt = deg[gi];
    const unsigned char* nb = nbr + (size_t)gi * NBR_CAP;
    float a = 0.f;
    const float* xb = hs + (size_t)b_s * 128 * H_ + hd;
    for (int c = 0; c < cnt; ++c) a += xb[(size_t)nb[c] * H_];
    mout[(size_t)bi * H_ + hd] = __float2bfloat16(a);
}

// ---------------- hs.sum(axis=1) ----------------
__global__ __launch_bounds__(128) void k_hssum(const float* __restrict__ hs, float* __restrict__ hsum)
{
    const int b_s = blockIdx.x, hd = threadIdx.x;
    float v = 0.f;
    const float* r = hs + (size_t)b_s * 128 * H_ + hd;
    for (int i = 0; i < 128; ++i) v += r[(size_t)i * H_];
    hsum[(size_t)b_s * H_ + hd] = v;
}

// ---------------- segment max over 16 subgraphs per graph ----------------
__global__ __launch_bounds__(128) void k_maxpool(const float* __restrict__ hs2, float* __restrict__ pooled)
{
    const int g = blockIdx.x, hd = threadIdx.x;
    float m = -INFINITY;
    for (int s = 0; s < 16; ++s) m = fmaxf(m, hs2[((size_t)(g * 16 + s)) * H_ + hd]);
    pooled[(size_t)g * H_ + hd] = m;
}

// ---------------- final projection ----------------
__global__ __launch_bounds__(128) void k_out(const float* __restrict__ pooled2,
    const float* __restrict__ out_W, const float* __restrict__ out_b, float* __restrict__ out)
{
    __shared__ float red[128];
    const int g = blockIdx.x, hd = threadIdx.x;
    red[hd] = pooled2[(size_t)g * H_ + hd] * out_W[hd];
    __syncthreads();
    for (int s = 64; s > 0; s >>= 1) {
        if (hd < s) red[hd] += red[hd + s];
        __syncthreads();
    }
    if (hd == 0) out[g] = red[0] + out_b[0];
}

extern "C" void kernel_launch(void* const* d_in, const int* in_sizes, int n_in,
                              void* d_out, int out_size, void* d_ws, size_t ws_size,
                              hipStream_t stream)
{
    (void)in_sizes; (void)n_in; (void)out_size; (void)ws_size;
    const float* x     = (const float*)d_in[0];
    const float* adj   = (const float*)d_in[1];
    const float* idemb = (const float*)d_in[2];
    const float* in_W1 = (const float*)d_in[3];
    const float* in_b1 = (const float*)d_in[4];
    const float* in_W2 = (const float*)d_in[5];
    const float* in_b2 = (const float*)d_in[6];
    const float* in_g  = (const float*)d_in[7];
    const float* in_bn = (const float*)d_in[8];
    const float* gW1   = (const float*)d_in[9];
    const float* gb1   = (const float*)d_in[10];
    const float* gW2   = (const float*)d_in[11];
    const float* gb2   = (const float*)d_in[12];
    const float* gg    = (const float*)d_in[13];
    const float* gbn   = (const float*)d_in[14];
    const float* iW1   = (const float*)d_in[15];
    const float* ib1   = (const float*)d_in[16];
    const float* iW2   = (const float*)d_in[17];
    const float* ib2   = (const float*)d_in[18];
    const float* ig    = (const float*)d_in[19];
    const float* ibn   = (const float*)d_in[20];
    const float* glW1  = (const float*)d_in[21];
    const float* glb1  = (const float*)d_in[22];
    const float* glW2  = (const float*)d_in[23];
    const float* glb2  = (const float*)d_in[24];
    const float* glg   = (const float*)d_in[25];
    const float* glbn  = (const float*)d_in[26];
    const float* s1_W  = (const float*)d_in[27];
    const float* s1_b  = (const float*)d_in[28];
    const float* s2_W  = (const float*)d_in[29];
    const float* s2_b  = (const float*)d_in[30];
    const float* rW1   = (const float*)d_in[31];
    const float* rb1   = (const float*)d_in[32];
    const float* rW2   = (const float*)d_in[33];
    const float* rb2   = (const float*)d_in[34];
    const float* rg    = (const float*)d_in[35];
    const float* rbn   = (const float*)d_in[36];
    const float* out_W = (const float*)d_in[37];
    const float* out_b = (const float*)d_in[38];
    const int* subgs   = (const int*)d_in[39];
    const int* num_node= (const int*)d_in[41];
    const int* allperm = (const int*)d_in[42];

    // ---- workspace layout (peak ~122.7 MB, same budget as the passing R2 layout) ----
    const size_t MB_ = (size_t)512 * 128 * P_ * H_ * 2;        // 100,663,296: m1 / z2
    char* w = (char*)d_ws;
    bf16*  mz     = (bf16*)(w);                                // region A: m1 -> z2 (in-place)
    float* hsb    = (float*)(w);                               // region A reuse: hs (512,128,128) f32
    bf16*  ms     = (bf16*)(w + 33554432ull);                  // region A reuse: gl messages bf16 16.8MB
    bf16*  zm     = (bf16*)(w + MB_);                          // (512,128,128) bf16 = 16.8 MB
    bf16*  WT     = (bf16*)(w + MB_ + 16777216ull);            // 8 x (128x128) bf16 transposed
    char*  wc     = w + MB_ + 16777216ull + 262144ull;
    float* hb     = (float*)(wc);                              // h (32,128,128) f32  2 MB
    float* sb2    = (float*)(wc + 2097152ull);                 // t1 / g-layer msgs    2 MB
    float* hsum   = (float*)(wc + 4194304ull);                 // (512,128)
    float* hs2    = (float*)(wc + 4456448ull);                 // (512,128)
    float* pooled = (float*)(wc + 4718592ull);                 // (32,128)
    float* pooled2= (float*)(wc + 4734976ull);                 // (32,128)
    unsigned char* nbr = (unsigned char*)(wc + 4751360ull);    // 4096*48 u8
    int*   deg    = (int*)(wc + 4947968ull);                   // 4096 i32
    float* degf   = (float*)(wc + 4964352ull);                 // 4096 f32
    float* outp   = (float*)d_out;

    // prep: CSR + transposed bf16 weights
    k_csr<<<32, 128, 0, stream>>>(adj, nbr, deg, degf);
    k_wt8<<<1024, 128, 0, stream>>>(iW1, iW2, iW1 + 16384, iW2 + 16384,
                                    glW1, glW2, glW1 + 16384, glW2 + 16384, WT);

    // input embedding block: h = block(x)
    k_in_t1<<<4096, 128, 0, stream>>>(x, in_W1, in_b1, sb2);
    k_block<false, false><<<256, 128, 0, stream>>>(sb2, nullptr, hb,
        nullptr, nullptr, in_W2, in_b2, in_g, in_bn);

    // graph message passing (3 layers) on h — small, keep VALU path
    for (int l = 0; l < 3; ++l) {
        k_spmv<<<4096, 128, 0, stream>>>(adj, hb, sb2, 0);
        k_block<true, true><<<256, 128, 0, stream>>>(sb2, hb, hb,
            gW1 + l * 16384, gb1 + l * 128, gW2 + l * 16384, gb2 + l * 128,
            gg + l * 128, gbn + l * 128);
    }

    // ID layer 1: m1 closed-form -> MFMA MLP in-place -> z2 ; patch labeled residual
    k_m1<<<65536, 128, 0, stream>>>(adj, degf, subgs, allperm, idemb, mz);
    k_mlp_mfma<0><<<3072, 256, 0, stream>>>(mz, nullptr, mz, nullptr,
        WT, ib1, WT + 16384, ib2, ig, ibn);
    k_addself<<<2048, 128, 0, stream>>>(mz, subgs, allperm, idemb);

    // ID layer 2 fully fused -> zm (z3 never materialized)
    k_id2_fused<<<2048, 256, 0, stream>>>(mz, zm, nbr, deg, num_node,
        WT + 2 * 16384, ib1 + 128, WT + 3 * 16384, ib2 + 128, ig + 128, ibn + 128);

    // setmlp1 with gathered residual h[subgbatch] -> hsb (region A; z2 now dead)
    k_gemm_relu<true, bf16><<<4096, 128, 0, stream>>>(zm, hb, hsb, s1_W, s1_b);

    // global message passing on subgraph copies (2 layers): gather-spmv + MFMA MLP
    for (int l = 0; l < 2; ++l) {
        k_spm_gl<<<65536, 128, 0, stream>>>(hsb, ms, nbr, deg);
        k_mlp_mfma<2><<<512, 256, 0, stream>>>(ms, hsb, nullptr, hsb,
            WT + (4 + 2 * l) * 16384, glb1 + l * 128,
            WT + (5 + 2 * l) * 16384, glb2 + l * 128,
            glg + l * 128, glbn + l * 128);
    }

    // node sum -> setmlp2 -> segment max -> setmlp3 block -> output proj
    k_hssum<<<512, 128, 0, stream>>>(hsb, hsum);
    k_gemm_relu<false, float><<<32, 128, 0, stream>>>(hsum, nullptr, hs2, s2_W, s2_b);
    k_maxpool<<<32, 128, 0, stream>>>(hs2, pooled);
    k_block<true, true><<<2, 128, 0, stream>>>(pooled, pooled, pooled2,
        rW1, rb1, rW2, rb2, rg, rbn);
    k_out<<<32, 128, 0, stream>>>(pooled2, out_W, out_b, outp);
}